// Round 9
// baseline (816.501 us; speedup 1.0000x reference)
//
#include <hip/hip_runtime.h>
#include <hip/hip_bf16.h>

#define S_ 48
#define D_ 128
#define H_ 512
#define L_ 256
#define V_ 6000
#define SD_ 6144      // S*D
#define M3_ 3072      // 6*H permuted gate rows per tree
#define NWG_HALF 64   // WGs per dh-half barrier group

// barrier region layout (unsigned words), one region per recurrence dispatch
#define SB_ (S_ - 1)          // 47 in-kernel barriers
#define REGC_OFF 0            // [2][8]  per (dh, xcd) WG count
#define SETUP_OFF 16          // [2]     setup barrier
#define XARR_OFF 18           // [2][8][SB_] per-step per-XCD arrivals
#define GREADY_OFF (18 + 2*8*SB_)            // [2][SB_] flushed-XCD count
#define INVD_OFF (18 + 2*8*SB_ + 2*SB_)      // [2][8][SB_] inv-done flags
#define BAR_WORDS (18 + 2*8*SB_ + 2*SB_ + 2*8*SB_)

typedef __attribute__((ext_vector_type(8))) short short8;
typedef __attribute__((ext_vector_type(4))) float f32x4;
typedef __hip_bfloat16 bf16;

__device__ __forceinline__ float sigm(float x) { return 1.0f / (1.0f + __expf(-x)); }
__device__ __forceinline__ f32x4 zero4() { f32x4 z; z[0]=0.f; z[1]=0.f; z[2]=0.f; z[3]=0.f; return z; }

// async global->LDS, 16B per lane; LDS dest = wave-uniform base + lane*16
__device__ __forceinline__ void gl_lds16(const bf16* g, bf16* l) {
  __builtin_amdgcn_global_load_lds((const __attribute__((address_space(1))) void*)g,
                                   (__attribute__((address_space(3))) void*)l, 16, 0, 0);
}

// ---------------------------------------------------------------------------
// Prep kernels
// ---------------------------------------------------------------------------
struct PrepArgs {
  const float* wih[4]; const float* whh[4];
  const float* bih[4]; const float* bhh[4];
};

__global__ __launch_bounds__(64) void k_prep_w(PrepArgs pa, bf16* __restrict__ wihp,
                                               bf16* __restrict__ whhp,
                                               float* __restrict__ bgi,
                                               float* __restrict__ bghn) {
  const int R = blockIdx.x;
  const int tree = R / M3_;
  const int p = R - tree * M3_;
  const int j = p / 6;
  const int t6 = p - j * 6;
  const int sib = (t6 >= 3) ? 1 : 0;
  const int g = t6 - sib * 3;
  const int cell = tree * 2 + sib;
  const int srow = g * H_ + j;
  const float* wi = pa.wih[cell] + (size_t)srow * H_;
  const float* wh = pa.whh[cell] + (size_t)srow * H_;
  bf16* di = wihp + (size_t)R * H_;
  bf16* dh = whhp + (size_t)R * H_;
  const int k0 = threadIdx.x * 8;
  #pragma unroll
  for (int i = 0; i < 8; ++i) {
    di[k0 + i] = __float2bfloat16(wi[k0 + i]);
    dh[k0 + i] = __float2bfloat16(wh[k0 + i]);
  }
  if (threadIdx.x == 0) {
    float bi = pa.bih[cell][srow], bh = pa.bhh[cell][srow];
    bgi[R]  = bi + (g < 2 ? bh : 0.f);
    bghn[R] = (g == 2 ? bh : 0.f);
  }
}

__global__ void k_gather_x(const int* __restrict__ nodes, const float* __restrict__ emb,
                           bf16* __restrict__ X) {
  int i = blockIdx.x * 256 + threadIdx.x;
  if (i < SD_ * H_) {
    int sd = i >> 9, k = i & 511;
    X[i] = __float2bfloat16(emb[(size_t)nodes[sd] * H_ + k]);
  }
}

__global__ void k_cvt_bf16(const float* __restrict__ src, bf16* __restrict__ dst, int n) {
  int i = blockIdx.x * 256 + threadIdx.x;
  if (i < n) dst[i] = __float2bfloat16(src[i]);
}

// h(0): hf f32 [d][j]  +  HSTEPE[0] bf16 [jb][d][8]
__global__ void k_init_h(const float* __restrict__ init, float* __restrict__ hf,
                         bf16* __restrict__ hx0) {
  int i = blockIdx.x * 256 + threadIdx.x;
  if (i < D_ * H_) {
    int d = i >> 9, j = i & 511;
    float v = init[i];
    hf[i] = v;
    hx0[((j >> 3) * D_ + d) * 8 + (j & 7)] = __float2bfloat16(v);
  }
}

// ---------------------------------------------------------------------------
// bf16 GEMM, m97-style: global_load_lds(16B) staging into LINEAR LDS [128][64],
// 128x128 tile, BK=64, 4 waves of 64x64. C(M,N) = A(M,512)@B(N,512)^T + bias.
// ---------------------------------------------------------------------------
template<bool BIAS_ON_M, bool GUARD_N, bool CB16>
__global__ __launch_bounds__(256) void k_gemm(const bf16* __restrict__ A,
                                              const bf16* __restrict__ B,
                                              const float* __restrict__ bias,
                                              void* __restrict__ Cv, int M, int N) {
  constexpr int K = 512;
  __shared__ bf16 As[128 * 64];
  __shared__ bf16 Bs[128 * 64];
  const int tid = threadIdx.x;
  const int l = tid & 63, w = tid >> 6;
  const int gm0 = blockIdx.y * 128, gn0 = blockIdx.x * 128;
  const int wr = w >> 1, wc = w & 1;
  f32x4 acc[4][4];
  #pragma unroll
  for (int a = 0; a < 4; ++a)
    #pragma unroll
    for (int b = 0; b < 4; ++b) acc[a][b] = zero4();

  // staging geometry: per round r, wave stages rows rbase..rbase+7,
  // lane l -> row rbase+(l>>3), 16B at k-chunk (l&7)*8  (linear [row][64])
  const int srow_in_round = (w << 3) + (l >> 3);   // w*8 + l/8
  const int skl = (l & 7) * 8;

  for (int kt = 0; kt < K; kt += 64) {
    #pragma unroll
    for (int r = 0; r < 4; ++r) {
      int row = r * 32 + srow_in_round;
      gl_lds16(&A[(size_t)(gm0 + row) * K + kt + skl], As + (r * 32 + (w << 3)) * 64);
      int brow = gn0 + row;
      if (GUARD_N) brow = brow < N ? brow : N - 1;
      gl_lds16(&B[(size_t)brow * K + kt + skl], Bs + (r * 32 + (w << 3)) * 64);
    }
    asm volatile("s_waitcnt vmcnt(0)" ::: "memory");
    __syncthreads();
    #pragma unroll
    for (int kk = 0; kk < 64; kk += 32) {
      short8 af[4], bfr[4];
      const int kb = (kk + (l >> 4) * 8) * 2;
      #pragma unroll
      for (int mt = 0; mt < 4; ++mt) {
        int row = wr * 64 + mt * 16 + (l & 15);
        af[mt] = *reinterpret_cast<const short8*>(reinterpret_cast<const char*>(As) + row * 128 + kb);
      }
      #pragma unroll
      for (int nt = 0; nt < 4; ++nt) {
        int row = wc * 64 + nt * 16 + (l & 15);
        bfr[nt] = *reinterpret_cast<const short8*>(reinterpret_cast<const char*>(Bs) + row * 128 + kb);
      }
      #pragma unroll
      for (int mt = 0; mt < 4; ++mt)
        #pragma unroll
        for (int nt = 0; nt < 4; ++nt)
          acc[mt][nt] = __builtin_amdgcn_mfma_f32_16x16x32_bf16(af[mt], bfr[nt], acc[mt][nt], 0, 0, 0);
    }
    __syncthreads();
  }
  #pragma unroll
  for (int mt = 0; mt < 4; ++mt)
    #pragma unroll
    for (int nt = 0; nt < 4; ++nt)
      #pragma unroll
      for (int i = 0; i < 4; ++i) {
        int row = wr * 64 + mt * 16 + (l >> 4) * 4 + i;
        int col = wc * 64 + nt * 16 + (l & 15);
        int gr = gm0 + row, gc = gn0 + col;
        if (!GUARD_N || gc < N) {
          float v = acc[mt][nt][i] + (BIAS_ON_M ? bias[gr] : bias[gc]);
          if (CB16) ((bf16*)Cv)[(size_t)gr * N + gc] = __float2bfloat16(v);
          else      ((float*)Cv)[(size_t)gr * N + gc] = v;
        }
      }
}

// ---------------------------------------------------------------------------
// Tree-GRU recurrence — BYTE-IDENTICAL to R7 (proven). h(t) in HSTEP[t]
// (fresh buffer per step), [jb][d][8] bf16, plain loads/stores. Barrier:
// per-XCD designated WG does the single RELEASE wbl2 + ACQUIRE inv.
// ---------------------------------------------------------------------------
__global__ __launch_bounds__(256) void k_recur(const bf16* __restrict__ whhp,
                                               const bf16* __restrict__ giT,
                                               const float* __restrict__ bghn,
                                               const int* __restrict__ edges,
                                               float* __restrict__ hf,
                                               bf16* __restrict__ hsteps,
                                               bf16* __restrict__ outs,
                                               unsigned* __restrict__ bar) {
  __shared__ float lds_p[4][64][52];
  const int tid = threadIdx.x, l = tid & 63, w = tid >> 6;
  const int ms = blockIdx.x >> 1, dh = blockIdx.x & 1;
  const int kw = w * 128;

  unsigned my_xcc = 0, my_desig = 0, my_xcdcnt = 0, my_nxcd = 0;
  if (tid == 0) {
    asm volatile("s_getreg_b32 %0, hwreg(HW_REG_XCC_ID)" : "=s"(my_xcc));
    my_xcc &= 7;
    unsigned prev = __hip_atomic_fetch_add(bar + REGC_OFF + dh * 8 + my_xcc, 1u,
                                           __ATOMIC_RELAXED, __HIP_MEMORY_SCOPE_AGENT);
    my_desig = (prev == 0);
    unsigned* sb = bar + SETUP_OFF + dh;
    __hip_atomic_fetch_add(sb, 1u, __ATOMIC_RELEASE, __HIP_MEMORY_SCOPE_AGENT);
    while (__hip_atomic_load(sb, __ATOMIC_RELAXED, __HIP_MEMORY_SCOPE_AGENT) < NWG_HALF)
      __builtin_amdgcn_s_sleep(2);
    __builtin_amdgcn_fence(__ATOMIC_ACQUIRE, "agent");
    my_xcdcnt = __hip_atomic_load(bar + REGC_OFF + dh * 8 + my_xcc,
                                  __ATOMIC_RELAXED, __HIP_MEMORY_SCOPE_AGENT);
    #pragma unroll
    for (int x = 0; x < 8; ++x)
      my_nxcd += (__hip_atomic_load(bar + REGC_OFF + dh * 8 + x,
                                    __ATOMIC_RELAXED, __HIP_MEMORY_SCOPE_AGENT) > 0u) ? 1u : 0u;
  }

  short8 areg[3][4];
  #pragma unroll
  for (int mt = 0; mt < 3; ++mt)
    #pragma unroll
    for (int ks = 0; ks < 4; ++ks) {
      int row = ms * 48 + mt * 16 + (l & 15);
      int k = kw + ks * 32 + (l >> 4) * 8;
      areg[mt][ks] = *reinterpret_cast<const short8*>(&whhp[(size_t)row * H_ + k]);
    }

  const int dl = tid >> 2;
  const int jp = (tid & 3) * 2;
  const int dg = dh * 64 + dl;
  const int jg0 = ms * 8 + jp;
  float bgh[12];
  #pragma unroll
  for (int q = 0; q < 12; ++q) bgh[q] = bghn[ms * 48 + jp * 6 + q];
  float hstate[2] = { hf[dg * H_ + jg0], hf[dg * H_ + jg0 + 1] };
  const bf16* gbase = giT + (size_t)(ms * 48 + jp * 6) * SD_ + dg;

  float gic[12]; int edc;
  #pragma unroll
  for (int q = 0; q < 12; ++q) gic[q] = __bfloat162float(gbase[(size_t)q * SD_]);
  edc = edges[dg];

  #pragma unroll 1
  for (int t = 0; t < S_; ++t) {
    float gin[12]; int edn;
    if (t + 1 < S_) {
      #pragma unroll
      for (int q = 0; q < 12; ++q) gin[q] = __bfloat162float(gbase[(size_t)q * SD_ + (t + 1) * D_]);
      edn = edges[(t + 1) * D_ + dg];
    } else {
      edn = 0;
      #pragma unroll
      for (int q = 0; q < 12; ++q) gin[q] = 0.f;
    }

    const bf16* hb = hsteps + (size_t)t * (D_ * H_);
    bf16* hnb = hsteps + (size_t)(t + 1) * (D_ * H_);

    short8 bfr[4][4];
    #pragma unroll
    for (int ks = 0; ks < 4; ++ks)
      #pragma unroll
      for (int nt = 0; nt < 4; ++nt) {
        int jb = w * 16 + ks * 4 + (l >> 4);
        int d = dh * 64 + nt * 16 + (l & 15);
        bfr[ks][nt] = *reinterpret_cast<const short8*>(hb + ((size_t)jb * D_ + d) * 8);
      }

    f32x4 acc[3][4];
    #pragma unroll
    for (int a = 0; a < 3; ++a)
      #pragma unroll
      for (int b = 0; b < 4; ++b) acc[a][b] = zero4();
    #pragma unroll
    for (int ks = 0; ks < 4; ++ks)
      #pragma unroll
      for (int mt = 0; mt < 3; ++mt)
        #pragma unroll
        for (int nt = 0; nt < 4; ++nt)
          acc[mt][nt] = __builtin_amdgcn_mfma_f32_16x16x32_bf16(areg[mt][ks], bfr[ks][nt], acc[mt][nt], 0, 0, 0);

    __syncthreads();
    #pragma unroll
    for (int mt = 0; mt < 3; ++mt)
      #pragma unroll
      for (int nt = 0; nt < 4; ++nt) {
        int col = nt * 16 + (l & 15);
        int r0 = mt * 16 + (l >> 4) * 4;
        *reinterpret_cast<f32x4*>(&lds_p[w][col][r0]) = acc[mt][nt];
      }
    __syncthreads();

    unsigned hpack;
    #pragma unroll
    for (int sl = 0; sl < 2; ++sl) {
      float gh[6];
      #pragma unroll
      for (int q = 0; q < 6; ++q) {
        int r = (jp + sl) * 6 + q;
        gh[q] = lds_p[0][dl][r] + lds_p[1][dl][r] + lds_p[2][dl][r]
              + lds_p[3][dl][r] + bgh[sl * 6 + q];
      }
      float rc = sigm(gic[sl * 6 + 0] + gh[0]);
      float zc = sigm(gic[sl * 6 + 1] + gh[1]);
      float nc = tanhf(gic[sl * 6 + 2] + rc * gh[2]);
      float rs = sigm(gic[sl * 6 + 3] + gh[3]);
      float zs = sigm(gic[sl * 6 + 4] + gh[4]);
      float ns = tanhf(gic[sl * 6 + 5] + rs * gh[5]);
      float ho = hstate[sl];
      float hc = (1.f - zc) * nc + zc * ho;
      float hs = (1.f - zs) * ns + zs * ho;
      float hv = (edc != 0) ? hc : hs;
      hstate[sl] = hv;
      bf16 hvb = __float2bfloat16(hv);
      reinterpret_cast<unsigned short*>(&hpack)[sl] = *reinterpret_cast<unsigned short*>(&hvb);
    }
    *reinterpret_cast<unsigned*>(hnb + ((size_t)ms * D_ + dg) * 8 + jp) = hpack;
    if (outs) {
      *reinterpret_cast<unsigned*>(&outs[(size_t)t * (D_ * H_) + dg * H_ + jg0]) = hpack;
    }
    edc = edn;
    #pragma unroll
    for (int q = 0; q < 12; ++q) gic[q] = gin[q];

    if (t + 1 < S_) {
      __syncthreads();
      if (tid == 0) {
        unsigned* xa = bar + XARR_OFF + ((dh * 8 + my_xcc) * SB_ + t);
        unsigned* gr = bar + GREADY_OFF + (dh * SB_ + t);
        unsigned* id = bar + INVD_OFF + ((dh * 8 + my_xcc) * SB_ + t);
        __hip_atomic_fetch_add(xa, 1u, __ATOMIC_RELAXED, __HIP_MEMORY_SCOPE_AGENT);
        if (my_desig) {
          while (__hip_atomic_load(xa, __ATOMIC_RELAXED, __HIP_MEMORY_SCOPE_AGENT) < my_xcdcnt)
            __builtin_amdgcn_s_sleep(1);
          __hip_atomic_fetch_add(gr, 1u, __ATOMIC_RELEASE, __HIP_MEMORY_SCOPE_AGENT);
          while (__hip_atomic_load(gr, __ATOMIC_RELAXED, __HIP_MEMORY_SCOPE_AGENT) < my_nxcd)
            __builtin_amdgcn_s_sleep(1);
          __builtin_amdgcn_fence(__ATOMIC_ACQUIRE, "agent");
          __hip_atomic_fetch_add(id, 1u, __ATOMIC_RELAXED, __HIP_MEMORY_SCOPE_AGENT);
        } else {
          while (__hip_atomic_load(id, __ATOMIC_RELAXED, __HIP_MEMORY_SCOPE_AGENT) < 1u)
            __builtin_amdgcn_s_sleep(1);
          __builtin_amdgcn_fence(__ATOMIC_ACQUIRE, "workgroup");
        }
      }
      __syncthreads();
    }
  }
  hf[dg * H_ + jg0]     = hstate[0];
  hf[dg * H_ + jg0 + 1] = hstate[1];
}

// mean/logv/z from final encoder h (f32)
__global__ __launch_bounds__(256) void k_latent(const float* __restrict__ hf,
    const float* __restrict__ h2mW, const float* __restrict__ h2mB,
    const float* __restrict__ h2lW, const float* __restrict__ h2lB,
    const float* __restrict__ eps, float* __restrict__ om, float* __restrict__ ov,
    float* __restrict__ oz, float* __restrict__ zf) {
  __shared__ float hrow[H_];
  const int d = blockIdx.x;
  for (int k = threadIdx.x; k < H_; k += 256) hrow[k] = hf[d * H_ + k];
  __syncthreads();
  const int lc = threadIdx.x;   // L_ == 256
  const float* wm = &h2mW[(size_t)lc * H_];
  const float* wl = &h2lW[(size_t)lc * H_];
  float m = 0.f, v = 0.f;
  for (int k = 0; k < H_; ++k) { float h = hrow[k]; m += h * wm[k]; v += h * wl[k]; }
  m += h2mB[lc]; v += h2lB[lc];
  float z = eps[d * L_ + lc] * __expf(0.5f * v) + m;
  om[d * L_ + lc] = m; ov[d * L_ + lc] = v; oz[d * L_ + lc] = z; zf[d * L_ + lc] = z;
}

__global__ __launch_bounds__(256) void k_decinit(const float* __restrict__ zf,
    const float* __restrict__ l2hW, const float* __restrict__ l2hB,
    float* __restrict__ hf, bf16* __restrict__ hx0) {
  __shared__ float zrow[L_];
  const int d = blockIdx.x;
  if (threadIdx.x < L_) zrow[threadIdx.x] = zf[d * L_ + threadIdx.x];
  __syncthreads();
  for (int j = threadIdx.x; j < H_; j += 256) {
    const float* wr = &l2hW[(size_t)j * L_];
    float a = 0.f;
    for (int k = 0; k < L_; ++k) a += zrow[k] * wr[k];
    a += l2hB[j];
    hf[d * H_ + j] = a;
    hx0[((j >> 3) * D_ + d) * 8 + (j & 7)] = __float2bfloat16(a);
  }
}

// log-softmax over V=6000, float4-vectorized (1500 f32x4 per row)
__global__ __launch_bounds__(256) void k_logsoftmax(float* __restrict__ lg) {
  __shared__ float buf[V_];
  __shared__ float redm[4], reds[4];
  constexpr int V4 = V_ / 4;   // 1500
  const size_t base4 = (size_t)blockIdx.x * V4;
  float4* g4 = reinterpret_cast<float4*>(lg) + base4;
  float4* b4 = reinterpret_cast<float4*>(buf);
  const int tid = threadIdx.x;
  float lmax = -3.0e38f;
  for (int i = tid; i < V4; i += 256) {
    float4 v = g4[i]; b4[i] = v;
    lmax = fmaxf(fmaxf(fmaxf(lmax, v.x), fmaxf(v.y, v.z)), v.w);
  }
  #pragma unroll
  for (int off = 32; off > 0; off >>= 1) lmax = fmaxf(lmax, __shfl_down(lmax, off, 64));
  if ((tid & 63) == 0) redm[tid >> 6] = lmax;
  __syncthreads();
  const float gmax = fmaxf(fmaxf(redm[0], redm[1]), fmaxf(redm[2], redm[3]));
  float s = 0.f;
  for (int i = tid; i < V4; i += 256) {
    float4 v = b4[i];
    s += __expf(v.x - gmax) + __expf(v.y - gmax) + __expf(v.z - gmax) + __expf(v.w - gmax);
  }
  #pragma unroll
  for (int off = 32; off > 0; off >>= 1) s += __shfl_down(s, off, 64);
  if ((tid & 63) == 0) reds[tid >> 6] = s;
  __syncthreads();
  const float lse = gmax + __logf(reds[0] + reds[1] + reds[2] + reds[3]);
  for (int i = tid; i < V4; i += 256) {
    float4 v = b4[i];
    v.x -= lse; v.y -= lse; v.z -= lse; v.w -= lse;
    g4[i] = v;
  }
}

// ---------------------------------------------------------------------------
extern "C" void kernel_launch(void* const* d_in, const int* in_sizes, int n_in,
                              void* d_out, int out_size, void* d_ws, size_t ws_size,
                              hipStream_t stream) {
  const int* nodes = (const int*)d_in[0];
  const int* edges = (const int*)d_in[1];
  const float* emb = (const float*)d_in[2];
  PrepArgs pa;
  for (int c = 0; c < 4; ++c) {
    pa.wih[c] = (const float*)d_in[3 + c * 4 + 0];
    pa.whh[c] = (const float*)d_in[3 + c * 4 + 1];
    pa.bih[c] = (const float*)d_in[3 + c * 4 + 2];
    pa.bhh[c] = (const float*)d_in[3 + c * 4 + 3];
  }
  const float* h2mW = (const float*)d_in[19];
  const float* h2mB = (const float*)d_in[20];
  const float* h2lW = (const float*)d_in[21];
  const float* h2lB = (const float*)d_in[22];
  const float* l2hW = (const float*)d_in[23];
  const float* l2hB = (const float*)d_in[24];
  const float* o2vW = (const float*)d_in[25];
  const float* o2vB = (const float*)d_in[26];
  const float* enc_init = (const float*)d_in[27];
  const float* eps = (const float*)d_in[28];

  char* ws = (char*)d_ws;
  size_t off = 0;
  bf16* WIHP = (bf16*)(ws + off); off += (size_t)2 * M3_ * H_ * 2;
  bf16* WHHP = (bf16*)(ws + off); off += (size_t)2 * M3_ * H_ * 2;
  float* BGI  = (float*)(ws + off); off += (size_t)2 * M3_ * 4;
  float* BGHN = (float*)(ws + off); off += (size_t)2 * M3_ * 4;
  bf16* XB   = (bf16*)(ws + off); off += (size_t)SD_ * H_ * 2;
  bf16* O2VB = (bf16*)(ws + off); off += (size_t)V_ * H_ * 2;
  float* HF  = (float*)(ws + off); off += (size_t)D_ * H_ * 4;
  bf16* HSTEPE = (bf16*)(ws + off); off += (size_t)(S_ + 1) * D_ * H_ * 2;  // 6.4 MB
  bf16* HSTEPD = (bf16*)(ws + off); off += (size_t)(S_ + 1) * D_ * H_ * 2;  // 6.4 MB
  float* ZF  = (float*)(ws + off); off += (size_t)D_ * L_ * 4;
  bf16* OUTS = (bf16*)(ws + off); off += (size_t)S_ * D_ * H_ * 2;
  bf16* GITB = (bf16*)(ws + off); off += (size_t)M3_ * SD_ * 2;             // 37.7 MB
  unsigned* BAR = (unsigned*)(ws + off); off += 2 * BAR_WORDS * sizeof(unsigned);
  (void)ws_size; (void)in_sizes; (void)n_in; (void)out_size;

  float* out_logp = (float*)d_out;
  float* out_mean = out_logp + (size_t)SD_ * V_;
  float* out_logv = out_mean + (size_t)D_ * L_;
  float* out_z    = out_logv + (size_t)D_ * L_;

  // zero barrier counters every call (ws not re-poisoned between replays)
  hipMemsetAsync(BAR, 0, 2 * BAR_WORDS * sizeof(unsigned), stream);

  // prep
  hipLaunchKernelGGL(k_prep_w, dim3(2 * M3_), dim3(64), 0, stream, pa, WIHP, WHHP, BGI, BGHN);
  hipLaunchKernelGGL(k_gather_x, dim3((SD_ * H_ + 255) / 256), dim3(256), 0, stream, nodes, emb, XB);
  hipLaunchKernelGGL(k_cvt_bf16, dim3((V_ * H_ + 255) / 256), dim3(256), 0, stream, o2vW, O2VB, V_ * H_);
  hipLaunchKernelGGL(k_init_h, dim3((D_ * H_ + 255) / 256), dim3(256), 0, stream, enc_init, HF, HSTEPE);

  // encoder: gi GEMM (bf16 out) + recurrence
  hipLaunchKernelGGL((k_gemm<true, false, true>), dim3(SD_ / 128, M3_ / 128), dim3(256), 0, stream,
                     WIHP, XB, BGI, (void*)GITB, M3_, SD_);
  {
    const bf16* whhpE = WHHP; const bf16* gitp = GITB; const float* bghnE = BGHN;
    float* hfp = HF; bf16* hstep = HSTEPE; bf16* outs0 = nullptr;
    const int* edg = edges; unsigned* barE = BAR;
    void* args[] = {(void*)&whhpE, (void*)&gitp, (void*)&bghnE, (void*)&edg,
                    (void*)&hfp, (void*)&hstep, (void*)&outs0, (void*)&barE};
    hipLaunchCooperativeKernel((const void*)k_recur, dim3(128), dim3(256), args, 0, stream);
  }

  hipLaunchKernelGGL(k_latent, dim3(D_), dim3(256), 0, stream, HF, h2mW, h2mB, h2lW, h2lB,
                     eps, out_mean, out_logv, out_z, ZF);
  hipLaunchKernelGGL(k_decinit, dim3(D_), dim3(256), 0, stream, ZF, l2hW, l2hB, HF, HSTEPD);

  // decoder: gi GEMM + recurrence (writes OUTS)
  hipLaunchKernelGGL((k_gemm<true, false, true>), dim3(SD_ / 128, M3_ / 128), dim3(256), 0, stream,
                     WIHP + (size_t)M3_ * H_, XB, BGI + M3_, (void*)GITB, M3_, SD_);
  {
    const bf16* whhpD = WHHP + (size_t)M3_ * H_; const bf16* gitp = GITB;
    const float* bghnD = BGHN + M3_;
    float* hfp = HF; bf16* hstep = HSTEPD; bf16* outsP = OUTS;
    const int* edg = edges; unsigned* barD = BAR + BAR_WORDS;
    void* args[] = {(void*)&whhpD, (void*)&gitp, (void*)&bghnD, (void*)&edg,
                    (void*)&hfp, (void*)&hstep, (void*)&outsP, (void*)&barD};
    hipLaunchCooperativeKernel((const void*)k_recur, dim3(128), dim3(256), args, 0, stream);
  }

  // logits + log_softmax (in-place in d_out)
  hipLaunchKernelGGL((k_gemm<false, true, false>), dim3((V_ + 127) / 128, SD_ / 128), dim3(256), 0, stream,
                     OUTS, O2VB, o2vB, (void*)out_logp, SD_, V_);
  hipLaunchKernelGGL(k_logsoftmax, dim3(SD_), dim3(256), 0, stream, out_logp);
}

// Round 11
// 808.982 us; speedup vs baseline: 1.0093x; 1.0093x over previous
//
#include <hip/hip_runtime.h>
#include <hip/hip_bf16.h>

#define S_ 48
#define D_ 128
#define H_ 512
#define L_ 256
#define V_ 6000
#define SD_ 6144      // S*D
#define M3_ 3072      // 6*H permuted gate rows per tree
#define NWG_HALF 64   // WGs per dh-half barrier group

// barrier region layout (unsigned words), one region per recurrence dispatch
#define SB_ (S_ - 1)          // 47 in-kernel barriers
#define REGC_OFF 0            // [2][8]  per (dh, xcd) WG count
#define SETUP_OFF 16          // [2]     setup barrier
#define XARR_OFF 18           // [2][8][SB_] per-step per-XCD arrivals
#define GREADY_OFF (18 + 2*8*SB_)            // [2][SB_] flushed-XCD count
#define INVD_OFF (18 + 2*8*SB_ + 2*SB_)      // [2][8][SB_] inv-done flags
#define BAR_WORDS (18 + 2*8*SB_ + 2*SB_ + 2*8*SB_)

typedef __attribute__((ext_vector_type(8))) short short8;
typedef __attribute__((ext_vector_type(4))) float f32x4;
typedef __hip_bfloat16 bf16;

__device__ __forceinline__ float sigm(float x) { return 1.0f / (1.0f + __expf(-x)); }
__device__ __forceinline__ f32x4 zero4() { f32x4 z; z[0]=0.f; z[1]=0.f; z[2]=0.f; z[3]=0.f; return z; }

// async global->LDS, 16B per lane; LDS dest = wave-uniform base + lane*16
__device__ __forceinline__ void gl_lds16(const bf16* g, bf16* l) {
  __builtin_amdgcn_global_load_lds((const __attribute__((address_space(1))) void*)g,
                                   (__attribute__((address_space(3))) void*)l, 16, 0, 0);
}

// ---------------------------------------------------------------------------
// Prep kernels (vectorized)
// ---------------------------------------------------------------------------
struct PrepArgs {
  const float* wih[4]; const float* whh[4];
  const float* bih[4]; const float* bhh[4];
};

__global__ __launch_bounds__(64) void k_prep_w(PrepArgs pa, bf16* __restrict__ wihp,
                                               bf16* __restrict__ whhp,
                                               float* __restrict__ bgi,
                                               float* __restrict__ bghn) {
  const int R = blockIdx.x;
  const int tree = R / M3_;
  const int p = R - tree * M3_;
  const int j = p / 6;
  const int t6 = p - j * 6;
  const int sib = (t6 >= 3) ? 1 : 0;
  const int g = t6 - sib * 3;
  const int cell = tree * 2 + sib;
  const int srow = g * H_ + j;
  const float* wi = pa.wih[cell] + (size_t)srow * H_;
  const float* wh = pa.whh[cell] + (size_t)srow * H_;
  const int k0 = threadIdx.x * 8;
  float4 a0 = *reinterpret_cast<const float4*>(wi + k0);
  float4 a1 = *reinterpret_cast<const float4*>(wi + k0 + 4);
  float4 b0 = *reinterpret_cast<const float4*>(wh + k0);
  float4 b1 = *reinterpret_cast<const float4*>(wh + k0 + 4);
  short8 vi, vh;
  {
    float fa[8] = {a0.x,a0.y,a0.z,a0.w,a1.x,a1.y,a1.z,a1.w};
    float fb[8] = {b0.x,b0.y,b0.z,b0.w,b1.x,b1.y,b1.z,b1.w};
    #pragma unroll
    for (int i = 0; i < 8; ++i) {
      bf16 t1 = __float2bfloat16(fa[i]); vi[i] = *reinterpret_cast<short*>(&t1);
      bf16 t2 = __float2bfloat16(fb[i]); vh[i] = *reinterpret_cast<short*>(&t2);
    }
  }
  *reinterpret_cast<short8*>(wihp + (size_t)R * H_ + k0) = vi;
  *reinterpret_cast<short8*>(whhp + (size_t)R * H_ + k0) = vh;
  if (threadIdx.x == 0) {
    float bi = pa.bih[cell][srow], bh = pa.bhh[cell][srow];
    bgi[R]  = bi + (g < 2 ? bh : 0.f);
    bghn[R] = (g == 2 ? bh : 0.f);
  }
}

// 8 elements per thread
__global__ void k_gather_x(const int* __restrict__ nodes, const float* __restrict__ emb,
                           bf16* __restrict__ X) {
  int i8 = blockIdx.x * 256 + threadIdx.x;
  if (i8 < SD_ * H_ / 8) {
    int sd = i8 >> 6, k = (i8 & 63) * 8;
    const float* src = emb + (size_t)nodes[sd] * H_ + k;
    float4 a0 = *reinterpret_cast<const float4*>(src);
    float4 a1 = *reinterpret_cast<const float4*>(src + 4);
    float fa[8] = {a0.x,a0.y,a0.z,a0.w,a1.x,a1.y,a1.z,a1.w};
    short8 v;
    #pragma unroll
    for (int i = 0; i < 8; ++i) { bf16 t = __float2bfloat16(fa[i]); v[i] = *reinterpret_cast<short*>(&t); }
    *reinterpret_cast<short8*>(X + (size_t)i8 * 8) = v;
  }
}

// 8 elements per thread; n divisible by 8
__global__ void k_cvt_bf16(const float* __restrict__ src, bf16* __restrict__ dst, int n) {
  int i8 = blockIdx.x * 256 + threadIdx.x;
  if (i8 < n / 8) {
    const float* s = src + (size_t)i8 * 8;
    float4 a0 = *reinterpret_cast<const float4*>(s);
    float4 a1 = *reinterpret_cast<const float4*>(s + 4);
    float fa[8] = {a0.x,a0.y,a0.z,a0.w,a1.x,a1.y,a1.z,a1.w};
    short8 v;
    #pragma unroll
    for (int i = 0; i < 8; ++i) { bf16 t = __float2bfloat16(fa[i]); v[i] = *reinterpret_cast<short*>(&t); }
    *reinterpret_cast<short8*>(dst + (size_t)i8 * 8) = v;
  }
}

// h(0): hf f32 [d][j]  +  HSTEPE[0] bf16 [jb][d][8]
__global__ void k_init_h(const float* __restrict__ init, float* __restrict__ hf,
                         bf16* __restrict__ hx0) {
  int i = blockIdx.x * 256 + threadIdx.x;
  if (i < D_ * H_) {
    int d = i >> 9, j = i & 511;
    float v = init[i];
    hf[i] = v;
    hx0[((j >> 3) * D_ + d) * 8 + (j & 7)] = __float2bfloat16(v);
  }
}

// ---------------------------------------------------------------------------
// bf16 GEMM, m97-style: global_load_lds(16B) staging into LINEAR LDS [128][64],
// 128x128 tile, BK=64, 4 waves of 64x64. C(M,N) = A(M,512)@B(N,512)^T + bias.
// ---------------------------------------------------------------------------
template<bool BIAS_ON_M, bool GUARD_N, bool CB16>
__global__ __launch_bounds__(256) void k_gemm(const bf16* __restrict__ A,
                                              const bf16* __restrict__ B,
                                              const float* __restrict__ bias,
                                              void* __restrict__ Cv, int M, int N) {
  constexpr int K = 512;
  __shared__ bf16 As[128 * 64];
  __shared__ bf16 Bs[128 * 64];
  const int tid = threadIdx.x;
  const int l = tid & 63, w = tid >> 6;
  const int gm0 = blockIdx.y * 128, gn0 = blockIdx.x * 128;
  const int wr = w >> 1, wc = w & 1;
  f32x4 acc[4][4];
  #pragma unroll
  for (int a = 0; a < 4; ++a)
    #pragma unroll
    for (int b = 0; b < 4; ++b) acc[a][b] = zero4();

  const int srow_in_round = (w << 3) + (l >> 3);   // w*8 + l/8
  const int skl = (l & 7) * 8;

  for (int kt = 0; kt < K; kt += 64) {
    #pragma unroll
    for (int r = 0; r < 4; ++r) {
      int row = r * 32 + srow_in_round;
      gl_lds16(&A[(size_t)(gm0 + row) * K + kt + skl], As + (r * 32 + (w << 3)) * 64);
      int brow = gn0 + row;
      if (GUARD_N) brow = brow < N ? brow : N - 1;
      gl_lds16(&B[(size_t)brow * K + kt + skl], Bs + (r * 32 + (w << 3)) * 64);
    }
    asm volatile("s_waitcnt vmcnt(0)" ::: "memory");
    __syncthreads();
    #pragma unroll
    for (int kk = 0; kk < 64; kk += 32) {
      short8 af[4], bfr[4];
      const int kb = (kk + (l >> 4) * 8) * 2;
      #pragma unroll
      for (int mt = 0; mt < 4; ++mt) {
        int row = wr * 64 + mt * 16 + (l & 15);
        af[mt] = *reinterpret_cast<const short8*>(reinterpret_cast<const char*>(As) + row * 128 + kb);
      }
      #pragma unroll
      for (int nt = 0; nt < 4; ++nt) {
        int row = wc * 64 + nt * 16 + (l & 15);
        bfr[nt] = *reinterpret_cast<const short8*>(reinterpret_cast<const char*>(Bs) + row * 128 + kb);
      }
      #pragma unroll
      for (int mt = 0; mt < 4; ++mt)
        #pragma unroll
        for (int nt = 0; nt < 4; ++nt)
          acc[mt][nt] = __builtin_amdgcn_mfma_f32_16x16x32_bf16(af[mt], bfr[nt], acc[mt][nt], 0, 0, 0);
    }
    __syncthreads();
  }
  #pragma unroll
  for (int mt = 0; mt < 4; ++mt)
    #pragma unroll
    for (int nt = 0; nt < 4; ++nt)
      #pragma unroll
      for (int i = 0; i < 4; ++i) {
        int row = wr * 64 + mt * 16 + (l >> 4) * 4 + i;
        int col = wc * 64 + nt * 16 + (l & 15);
        int gr = gm0 + row, gc = gn0 + col;
        if (!GUARD_N || gc < N) {
          float v = acc[mt][nt][i] + (BIAS_ON_M ? bias[gr] : bias[gc]);
          if (CB16) ((bf16*)Cv)[(size_t)gr * N + gc] = __float2bfloat16(v);
          else      ((float*)Cv)[(size_t)gr * N + gc] = v;
        }
      }
}

// ---------------------------------------------------------------------------
// Tree-GRU recurrence — BYTE-IDENTICAL to R7 (proven protocol).
// ---------------------------------------------------------------------------
__global__ __launch_bounds__(256) void k_recur(const bf16* __restrict__ whhp,
                                               const bf16* __restrict__ giT,
                                               const float* __restrict__ bghn,
                                               const int* __restrict__ edges,
                                               float* __restrict__ hf,
                                               bf16* __restrict__ hsteps,
                                               bf16* __restrict__ outs,
                                               unsigned* __restrict__ bar) {
  __shared__ float lds_p[4][64][52];
  const int tid = threadIdx.x, l = tid & 63, w = tid >> 6;
  const int ms = blockIdx.x >> 1, dh = blockIdx.x & 1;
  const int kw = w * 128;

  unsigned my_xcc = 0, my_desig = 0, my_xcdcnt = 0, my_nxcd = 0;
  if (tid == 0) {
    asm volatile("s_getreg_b32 %0, hwreg(HW_REG_XCC_ID)" : "=s"(my_xcc));
    my_xcc &= 7;
    unsigned prev = __hip_atomic_fetch_add(bar + REGC_OFF + dh * 8 + my_xcc, 1u,
                                           __ATOMIC_RELAXED, __HIP_MEMORY_SCOPE_AGENT);
    my_desig = (prev == 0);
    unsigned* sb = bar + SETUP_OFF + dh;
    __hip_atomic_fetch_add(sb, 1u, __ATOMIC_RELEASE, __HIP_MEMORY_SCOPE_AGENT);
    while (__hip_atomic_load(sb, __ATOMIC_RELAXED, __HIP_MEMORY_SCOPE_AGENT) < NWG_HALF)
      __builtin_amdgcn_s_sleep(2);
    __builtin_amdgcn_fence(__ATOMIC_ACQUIRE, "agent");
    my_xcdcnt = __hip_atomic_load(bar + REGC_OFF + dh * 8 + my_xcc,
                                  __ATOMIC_RELAXED, __HIP_MEMORY_SCOPE_AGENT);
    #pragma unroll
    for (int x = 0; x < 8; ++x)
      my_nxcd += (__hip_atomic_load(bar + REGC_OFF + dh * 8 + x,
                                    __ATOMIC_RELAXED, __HIP_MEMORY_SCOPE_AGENT) > 0u) ? 1u : 0u;
  }

  short8 areg[3][4];
  #pragma unroll
  for (int mt = 0; mt < 3; ++mt)
    #pragma unroll
    for (int ks = 0; ks < 4; ++ks) {
      int row = ms * 48 + mt * 16 + (l & 15);
      int k = kw + ks * 32 + (l >> 4) * 8;
      areg[mt][ks] = *reinterpret_cast<const short8*>(&whhp[(size_t)row * H_ + k]);
    }

  const int dl = tid >> 2;
  const int jp = (tid & 3) * 2;
  const int dg = dh * 64 + dl;
  const int jg0 = ms * 8 + jp;
  float bgh[12];
  #pragma unroll
  for (int q = 0; q < 12; ++q) bgh[q] = bghn[ms * 48 + jp * 6 + q];
  float hstate[2] = { hf[dg * H_ + jg0], hf[dg * H_ + jg0 + 1] };
  const bf16* gbase = giT + (size_t)(ms * 48 + jp * 6) * SD_ + dg;

  float gic[12]; int edc;
  #pragma unroll
  for (int q = 0; q < 12; ++q) gic[q] = __bfloat162float(gbase[(size_t)q * SD_]);
  edc = edges[dg];

  #pragma unroll 1
  for (int t = 0; t < S_; ++t) {
    float gin[12]; int edn;
    if (t + 1 < S_) {
      #pragma unroll
      for (int q = 0; q < 12; ++q) gin[q] = __bfloat162float(gbase[(size_t)q * SD_ + (t + 1) * D_]);
      edn = edges[(t + 1) * D_ + dg];
    } else {
      edn = 0;
      #pragma unroll
      for (int q = 0; q < 12; ++q) gin[q] = 0.f;
    }

    const bf16* hb = hsteps + (size_t)t * (D_ * H_);
    bf16* hnb = hsteps + (size_t)(t + 1) * (D_ * H_);

    short8 bfr[4][4];
    #pragma unroll
    for (int ks = 0; ks < 4; ++ks)
      #pragma unroll
      for (int nt = 0; nt < 4; ++nt) {
        int jb = w * 16 + ks * 4 + (l >> 4);
        int d = dh * 64 + nt * 16 + (l & 15);
        bfr[ks][nt] = *reinterpret_cast<const short8*>(hb + ((size_t)jb * D_ + d) * 8);
      }

    f32x4 acc[3][4];
    #pragma unroll
    for (int a = 0; a < 3; ++a)
      #pragma unroll
      for (int b = 0; b < 4; ++b) acc[a][b] = zero4();
    #pragma unroll
    for (int ks = 0; ks < 4; ++ks)
      #pragma unroll
      for (int mt = 0; mt < 3; ++mt)
        #pragma unroll
        for (int nt = 0; nt < 4; ++nt)
          acc[mt][nt] = __builtin_amdgcn_mfma_f32_16x16x32_bf16(areg[mt][ks], bfr[ks][nt], acc[mt][nt], 0, 0, 0);

    __syncthreads();
    #pragma unroll
    for (int mt = 0; mt < 3; ++mt)
      #pragma unroll
      for (int nt = 0; nt < 4; ++nt) {
        int col = nt * 16 + (l & 15);
        int r0 = mt * 16 + (l >> 4) * 4;
        *reinterpret_cast<f32x4*>(&lds_p[w][col][r0]) = acc[mt][nt];
      }
    __syncthreads();

    unsigned hpack;
    #pragma unroll
    for (int sl = 0; sl < 2; ++sl) {
      float gh[6];
      #pragma unroll
      for (int q = 0; q < 6; ++q) {
        int r = (jp + sl) * 6 + q;
        gh[q] = lds_p[0][dl][r] + lds_p[1][dl][r] + lds_p[2][dl][r]
              + lds_p[3][dl][r] + bgh[sl * 6 + q];
      }
      float rc = sigm(gic[sl * 6 + 0] + gh[0]);
      float zc = sigm(gic[sl * 6 + 1] + gh[1]);
      float nc = tanhf(gic[sl * 6 + 2] + rc * gh[2]);
      float rs = sigm(gic[sl * 6 + 3] + gh[3]);
      float zs = sigm(gic[sl * 6 + 4] + gh[4]);
      float ns = tanhf(gic[sl * 6 + 5] + rs * gh[5]);
      float ho = hstate[sl];
      float hc = (1.f - zc) * nc + zc * ho;
      float hs = (1.f - zs) * ns + zs * ho;
      float hv = (edc != 0) ? hc : hs;
      hstate[sl] = hv;
      bf16 hvb = __float2bfloat16(hv);
      reinterpret_cast<unsigned short*>(&hpack)[sl] = *reinterpret_cast<unsigned short*>(&hvb);
    }
    *reinterpret_cast<unsigned*>(hnb + ((size_t)ms * D_ + dg) * 8 + jp) = hpack;
    if (outs) {
      *reinterpret_cast<unsigned*>(&outs[(size_t)t * (D_ * H_) + dg * H_ + jg0]) = hpack;
    }
    edc = edn;
    #pragma unroll
    for (int q = 0; q < 12; ++q) gic[q] = gin[q];

    if (t + 1 < S_) {
      __syncthreads();
      if (tid == 0) {
        unsigned* xa = bar + XARR_OFF + ((dh * 8 + my_xcc) * SB_ + t);
        unsigned* gr = bar + GREADY_OFF + (dh * SB_ + t);
        unsigned* id = bar + INVD_OFF + ((dh * 8 + my_xcc) * SB_ + t);
        __hip_atomic_fetch_add(xa, 1u, __ATOMIC_RELAXED, __HIP_MEMORY_SCOPE_AGENT);
        if (my_desig) {
          while (__hip_atomic_load(xa, __ATOMIC_RELAXED, __HIP_MEMORY_SCOPE_AGENT) < my_xcdcnt)
            __builtin_amdgcn_s_sleep(1);
          __hip_atomic_fetch_add(gr, 1u, __ATOMIC_RELEASE, __HIP_MEMORY_SCOPE_AGENT);
          while (__hip_atomic_load(gr, __ATOMIC_RELAXED, __HIP_MEMORY_SCOPE_AGENT) < my_nxcd)
            __builtin_amdgcn_s_sleep(1);
          __builtin_amdgcn_fence(__ATOMIC_ACQUIRE, "agent");
          __hip_atomic_fetch_add(id, 1u, __ATOMIC_RELAXED, __HIP_MEMORY_SCOPE_AGENT);
        } else {
          while (__hip_atomic_load(id, __ATOMIC_RELAXED, __HIP_MEMORY_SCOPE_AGENT) < 1u)
            __builtin_amdgcn_s_sleep(1);
          __builtin_amdgcn_fence(__ATOMIC_ACQUIRE, "workgroup");
        }
      }
      __syncthreads();
    }
  }
  hf[dg * H_ + jg0]     = hstate[0];
  hf[dg * H_ + jg0 + 1] = hstate[1];
}

// ---------------------------------------------------------------------------
// Fused latent + decoder-init: per d-row, mean/logv/z (L=256) then
// dec_init h (H=512) from z kept in LDS. Single block row; reads complete
// (into LDS + syncthreads) before any write to the same row.
// ---------------------------------------------------------------------------
__global__ __launch_bounds__(256) void k_latdec(const float* __restrict__ hf,
    const float* __restrict__ h2mW, const float* __restrict__ h2mB,
    const float* __restrict__ h2lW, const float* __restrict__ h2lB,
    const float* __restrict__ eps,
    const float* __restrict__ l2hW, const float* __restrict__ l2hB,
    float* __restrict__ om, float* __restrict__ ov, float* __restrict__ oz,
    float* __restrict__ hfD, bf16* __restrict__ hx0) {
  __shared__ float hrow[H_];
  __shared__ float zrow[L_];
  const int d = blockIdx.x;
  for (int k = threadIdx.x; k < H_; k += 256) hrow[k] = hf[d * H_ + k];
  __syncthreads();
  const int lc = threadIdx.x;   // L_ == 256
  {
    const float* wm = &h2mW[(size_t)lc * H_];
    const float* wl = &h2lW[(size_t)lc * H_];
    float m = 0.f, v = 0.f;
    for (int k = 0; k < H_; ++k) { float h = hrow[k]; m += h * wm[k]; v += h * wl[k]; }
    m += h2mB[lc]; v += h2lB[lc];
    float z = eps[d * L_ + lc] * __expf(0.5f * v) + m;
    om[d * L_ + lc] = m; ov[d * L_ + lc] = v; oz[d * L_ + lc] = z;
    zrow[lc] = z;
  }
  __syncthreads();
  for (int j = threadIdx.x; j < H_; j += 256) {
    const float* wr = &l2hW[(size_t)j * L_];
    float a = 0.f;
    for (int k = 0; k < L_; ++k) a += zrow[k] * wr[k];
    a += l2hB[j];
    hfD[d * H_ + j] = a;
    hx0[((j >> 3) * D_ + d) * 8 + (j & 7)] = __float2bfloat16(a);
  }
}

// log-softmax over V=6000, in-place f32, float4-vectorized (R9-proven)
__global__ __launch_bounds__(256) void k_logsoftmax(float* __restrict__ lg) {
  __shared__ float buf[V_];
  __shared__ float redm[4], reds[4];
  constexpr int V4 = V_ / 4;   // 1500
  const size_t base4 = (size_t)blockIdx.x * V4;
  float4* g4 = reinterpret_cast<float4*>(lg) + base4;
  float4* b4 = reinterpret_cast<float4*>(buf);
  const int tid = threadIdx.x;
  float lmax = -3.0e38f;
  for (int i = tid; i < V4; i += 256) {
    float4 v = g4[i]; b4[i] = v;
    lmax = fmaxf(fmaxf(fmaxf(lmax, v.x), fmaxf(v.y, v.z)), v.w);
  }
  #pragma unroll
  for (int off = 32; off > 0; off >>= 1) lmax = fmaxf(lmax, __shfl_down(lmax, off, 64));
  if ((tid & 63) == 0) redm[tid >> 6] = lmax;
  __syncthreads();
  const float gmax = fmaxf(fmaxf(redm[0], redm[1]), fmaxf(redm[2], redm[3]));
  float s = 0.f;
  for (int i = tid; i < V4; i += 256) {
    float4 v = b4[i];
    s += __expf(v.x - gmax) + __expf(v.y - gmax) + __expf(v.z - gmax) + __expf(v.w - gmax);
  }
  #pragma unroll
  for (int off = 32; off > 0; off >>= 1) s += __shfl_down(s, off, 64);
  if ((tid & 63) == 0) reds[tid >> 6] = s;
  __syncthreads();
  const float lse = gmax + __logf(reds[0] + reds[1] + reds[2] + reds[3]);
  for (int i = tid; i < V4; i += 256) {
    float4 v = b4[i];
    v.x -= lse; v.y -= lse; v.z -= lse; v.w -= lse;
    g4[i] = v;
  }
}

// ---------------------------------------------------------------------------
extern "C" void kernel_launch(void* const* d_in, const int* in_sizes, int n_in,
                              void* d_out, int out_size, void* d_ws, size_t ws_size,
                              hipStream_t stream) {
  const int* nodes = (const int*)d_in[0];
  const int* edges = (const int*)d_in[1];
  const float* emb = (const float*)d_in[2];
  PrepArgs pa;
  for (int c = 0; c < 4; ++c) {
    pa.wih[c] = (const float*)d_in[3 + c * 4 + 0];
    pa.whh[c] = (const float*)d_in[3 + c * 4 + 1];
    pa.bih[c] = (const float*)d_in[3 + c * 4 + 2];
    pa.bhh[c] = (const float*)d_in[3 + c * 4 + 3];
  }
  const float* h2mW = (const float*)d_in[19];
  const float* h2mB = (const float*)d_in[20];
  const float* h2lW = (const float*)d_in[21];
  const float* h2lB = (const float*)d_in[22];
  const float* l2hW = (const float*)d_in[23];
  const float* l2hB = (const float*)d_in[24];
  const float* o2vW = (const float*)d_in[25];
  const float* o2vB = (const float*)d_in[26];
  const float* enc_init = (const float*)d_in[27];
  const float* eps = (const float*)d_in[28];

  char* ws = (char*)d_ws;
  size_t off = 0;
  bf16* WIHP = (bf16*)(ws + off); off += (size_t)2 * M3_ * H_ * 2;
  bf16* WHHP = (bf16*)(ws + off); off += (size_t)2 * M3_ * H_ * 2;
  float* BGI  = (float*)(ws + off); off += (size_t)2 * M3_ * 4;
  float* BGHN = (float*)(ws + off); off += (size_t)2 * M3_ * 4;
  bf16* XB   = (bf16*)(ws + off); off += (size_t)SD_ * H_ * 2;
  bf16* O2VB = (bf16*)(ws + off); off += (size_t)V_ * H_ * 2;
  float* HF  = (float*)(ws + off); off += (size_t)D_ * H_ * 4;
  bf16* HSTEPE = (bf16*)(ws + off); off += (size_t)(S_ + 1) * D_ * H_ * 2;  // 6.4 MB
  bf16* HSTEPD = (bf16*)(ws + off); off += (size_t)(S_ + 1) * D_ * H_ * 2;  // 6.4 MB
  bf16* OUTS = (bf16*)(ws + off); off += (size_t)S_ * D_ * H_ * 2;
  bf16* GITB = (bf16*)(ws + off); off += (size_t)M3_ * SD_ * 2;             // 37.7 MB
  unsigned* BAR = (unsigned*)(ws + off); off += 2 * BAR_WORDS * sizeof(unsigned);
  (void)ws_size; (void)in_sizes; (void)n_in; (void)out_size;

  float* out_logp = (float*)d_out;
  float* out_mean = out_logp + (size_t)SD_ * V_;
  float* out_logv = out_mean + (size_t)D_ * L_;
  float* out_z    = out_logv + (size_t)D_ * L_;

  // zero barrier counters every call (ws not re-poisoned between replays)
  hipMemsetAsync(BAR, 0, 2 * BAR_WORDS * sizeof(unsigned), stream);

  // prep
  hipLaunchKernelGGL(k_prep_w, dim3(2 * M3_), dim3(64), 0, stream, pa, WIHP, WHHP, BGI, BGHN);
  hipLaunchKernelGGL(k_gather_x, dim3(SD_ * H_ / 8 / 256), dim3(256), 0, stream, nodes, emb, XB);
  hipLaunchKernelGGL(k_cvt_bf16, dim3(V_ * H_ / 8 / 256), dim3(256), 0, stream, o2vW, O2VB, V_ * H_);
  hipLaunchKernelGGL(k_init_h, dim3((D_ * H_ + 255) / 256), dim3(256), 0, stream, enc_init, HF, HSTEPE);

  // encoder: gi GEMM (bf16 out) + recurrence
  hipLaunchKernelGGL((k_gemm<true, false, true>), dim3(SD_ / 128, M3_ / 128), dim3(256), 0, stream,
                     WIHP, XB, BGI, (void*)GITB, M3_, SD_);
  {
    const bf16* whhpE = WHHP; const bf16* gitp = GITB; const float* bghnE = BGHN;
    float* hfp = HF; bf16* hstep = HSTEPE; bf16* outs0 = nullptr;
    const int* edg = edges; unsigned* barE = BAR;
    void* args[] = {(void*)&whhpE, (void*)&gitp, (void*)&bghnE, (void*)&edg,
                    (void*)&hfp, (void*)&hstep, (void*)&outs0, (void*)&barE};
    hipLaunchCooperativeKernel((const void*)k_recur, dim3(128), dim3(256), args, 0, stream);
  }

  // fused latent + decoder-init (writes mean/logv/z outputs + HF + HSTEPD[0])
  hipLaunchKernelGGL(k_latdec, dim3(D_), dim3(256), 0, stream, HF, h2mW, h2mB, h2lW, h2lB,
                     eps, l2hW, l2hB, out_mean, out_logv, out_z, HF, HSTEPD);

  // decoder: gi GEMM + recurrence (writes OUTS)
  hipLaunchKernelGGL((k_gemm<true, false, true>), dim3(SD_ / 128, M3_ / 128), dim3(256), 0, stream,
                     WIHP + (size_t)M3_ * H_, XB, BGI + M3_, (void*)GITB, M3_, SD_);
  {
    const bf16* whhpD = WHHP + (size_t)M3_ * H_; const bf16* gitp = GITB;
    const float* bghnD = BGHN + M3_;
    float* hfp = HF; bf16* hstep = HSTEPD; bf16* outsP = OUTS;
    const int* edg = edges; unsigned* barD = BAR + BAR_WORDS;
    void* args[] = {(void*)&whhpD, (void*)&gitp, (void*)&bghnD, (void*)&edg,
                    (void*)&hfp, (void*)&hstep, (void*)&outsP, (void*)&barD};
    hipLaunchCooperativeKernel((const void*)k_recur, dim3(128), dim3(256), args, 0, stream);
  }

  // logits (f32 directly into d_out) + in-place log_softmax (R9-proven)
  hipLaunchKernelGGL((k_gemm<false, true, false>), dim3((V_ + 127) / 128, SD_ / 128), dim3(256), 0, stream,
                     OUTS, O2VB, o2vB, (void*)out_logp, SD_, V_);
  hipLaunchKernelGGL(k_logsoftmax, dim3(SD_), dim3(256), 0, stream, out_logp);
}

// Round 13
// 806.996 us; speedup vs baseline: 1.0118x; 1.0025x over previous
//
#include <hip/hip_runtime.h>
#include <hip/hip_bf16.h>

#define S_ 48
#define D_ 128
#define H_ 512
#define L_ 256
#define V_ 6000
#define SD_ 6144      // S*D
#define M3_ 3072      // 6*H permuted gate rows per tree
#define NWG_HALF 64   // WGs per dh-half barrier group

// barrier region layout (unsigned words), one region per recurrence dispatch
#define SB_ (S_ - 1)          // 47 in-kernel barriers
#define REGC_OFF 0            // [2][8]  per (dh, xcd) WG count
#define SETUP_OFF 16          // [2]     setup barrier
#define XARR_OFF 18           // [2][8][SB_] per-step per-XCD arrivals
#define GREADY_OFF (18 + 2*8*SB_)            // [2][SB_] flushed-XCD count
#define INVD_OFF (18 + 2*8*SB_ + 2*SB_)      // [2][8][SB_] inv-done flags
#define BAR_WORDS (18 + 2*8*SB_ + 2*SB_ + 2*8*SB_)

typedef __attribute__((ext_vector_type(8))) short short8;
typedef __attribute__((ext_vector_type(4))) float f32x4;
typedef __hip_bfloat16 bf16;

__device__ __forceinline__ float sigm(float x) { return 1.0f / (1.0f + __expf(-x)); }
__device__ __forceinline__ f32x4 zero4() { f32x4 z; z[0]=0.f; z[1]=0.f; z[2]=0.f; z[3]=0.f; return z; }

// async global->LDS, 16B per lane; LDS dest = wave-uniform base + lane*16
__device__ __forceinline__ void gl_lds16(const bf16* g, bf16* l) {
  __builtin_amdgcn_global_load_lds((const __attribute__((address_space(1))) void*)g,
                                   (__attribute__((address_space(3))) void*)l, 16, 0, 0);
}

// ---------------------------------------------------------------------------
// Prep kernels (vectorized)
// ---------------------------------------------------------------------------
struct PrepArgs {
  const float* wih[4]; const float* whh[4];
  const float* bih[4]; const float* bhh[4];
};

__global__ __launch_bounds__(64) void k_prep_w(PrepArgs pa, bf16* __restrict__ wihp,
                                               bf16* __restrict__ whhp,
                                               float* __restrict__ bgi,
                                               float* __restrict__ bghn) {
  const int R = blockIdx.x;
  const int tree = R / M3_;
  const int p = R - tree * M3_;
  const int j = p / 6;
  const int t6 = p - j * 6;
  const int sib = (t6 >= 3) ? 1 : 0;
  const int g = t6 - sib * 3;
  const int cell = tree * 2 + sib;
  const int srow = g * H_ + j;
  const float* wi = pa.wih[cell] + (size_t)srow * H_;
  const float* wh = pa.whh[cell] + (size_t)srow * H_;
  const int k0 = threadIdx.x * 8;
  float4 a0 = *reinterpret_cast<const float4*>(wi + k0);
  float4 a1 = *reinterpret_cast<const float4*>(wi + k0 + 4);
  float4 b0 = *reinterpret_cast<const float4*>(wh + k0);
  float4 b1 = *reinterpret_cast<const float4*>(wh + k0 + 4);
  short8 vi, vh;
  {
    float fa[8] = {a0.x,a0.y,a0.z,a0.w,a1.x,a1.y,a1.z,a1.w};
    float fb[8] = {b0.x,b0.y,b0.z,b0.w,b1.x,b1.y,b1.z,b1.w};
    #pragma unroll
    for (int i = 0; i < 8; ++i) {
      bf16 t1 = __float2bfloat16(fa[i]); vi[i] = *reinterpret_cast<short*>(&t1);
      bf16 t2 = __float2bfloat16(fb[i]); vh[i] = *reinterpret_cast<short*>(&t2);
    }
  }
  *reinterpret_cast<short8*>(wihp + (size_t)R * H_ + k0) = vi;
  *reinterpret_cast<short8*>(whhp + (size_t)R * H_ + k0) = vh;
  if (threadIdx.x == 0) {
    float bi = pa.bih[cell][srow], bh = pa.bhh[cell][srow];
    bgi[R]  = bi + (g < 2 ? bh : 0.f);
    bghn[R] = (g == 2 ? bh : 0.f);
  }
}

// 8 elements per thread
__global__ void k_gather_x(const int* __restrict__ nodes, const float* __restrict__ emb,
                           bf16* __restrict__ X) {
  int i8 = blockIdx.x * 256 + threadIdx.x;
  if (i8 < SD_ * H_ / 8) {
    int sd = i8 >> 6, k = (i8 & 63) * 8;
    const float* src = emb + (size_t)nodes[sd] * H_ + k;
    float4 a0 = *reinterpret_cast<const float4*>(src);
    float4 a1 = *reinterpret_cast<const float4*>(src + 4);
    float fa[8] = {a0.x,a0.y,a0.z,a0.w,a1.x,a1.y,a1.z,a1.w};
    short8 v;
    #pragma unroll
    for (int i = 0; i < 8; ++i) { bf16 t = __float2bfloat16(fa[i]); v[i] = *reinterpret_cast<short*>(&t); }
    *reinterpret_cast<short8*>(X + (size_t)i8 * 8) = v;
  }
}

// 8 elements per thread; n divisible by 8
__global__ void k_cvt_bf16(const float* __restrict__ src, bf16* __restrict__ dst, int n) {
  int i8 = blockIdx.x * 256 + threadIdx.x;
  if (i8 < n / 8) {
    const float* s = src + (size_t)i8 * 8;
    float4 a0 = *reinterpret_cast<const float4*>(s);
    float4 a1 = *reinterpret_cast<const float4*>(s + 4);
    float fa[8] = {a0.x,a0.y,a0.z,a0.w,a1.x,a1.y,a1.z,a1.w};
    short8 v;
    #pragma unroll
    for (int i = 0; i < 8; ++i) { bf16 t = __float2bfloat16(fa[i]); v[i] = *reinterpret_cast<short*>(&t); }
    *reinterpret_cast<short8*>(dst + (size_t)i8 * 8) = v;
  }
}

// h(0): hf f32 [d][j]  +  HSTEPE[0] bf16 [jb][d][8]
__global__ void k_init_h(const float* __restrict__ init, float* __restrict__ hf,
                         bf16* __restrict__ hx0) {
  int i = blockIdx.x * 256 + threadIdx.x;
  if (i < D_ * H_) {
    int d = i >> 9, j = i & 511;
    float v = init[i];
    hf[i] = v;
    hx0[((j >> 3) * D_ + d) * 8 + (j & 7)] = __float2bfloat16(v);
  }
}

// ---------------------------------------------------------------------------
// bf16 GEMM, m97-style: global_load_lds(16B) staging into LINEAR LDS [128][64],
// 128x128 tile, BK=64, 4 waves of 64x64. C(M,N) = A(M,512)@B(N,512)^T + bias.
// ---------------------------------------------------------------------------
template<bool BIAS_ON_M, bool GUARD_N, bool CB16>
__global__ __launch_bounds__(256) void k_gemm(const bf16* __restrict__ A,
                                              const bf16* __restrict__ B,
                                              const float* __restrict__ bias,
                                              void* __restrict__ Cv, int M, int N) {
  constexpr int K = 512;
  __shared__ bf16 As[128 * 64];
  __shared__ bf16 Bs[128 * 64];
  const int tid = threadIdx.x;
  const int l = tid & 63, w = tid >> 6;
  const int gm0 = blockIdx.y * 128, gn0 = blockIdx.x * 128;
  const int wr = w >> 1, wc = w & 1;
  f32x4 acc[4][4];
  #pragma unroll
  for (int a = 0; a < 4; ++a)
    #pragma unroll
    for (int b = 0; b < 4; ++b) acc[a][b] = zero4();

  const int srow_in_round = (w << 3) + (l >> 3);   // w*8 + l/8
  const int skl = (l & 7) * 8;

  for (int kt = 0; kt < K; kt += 64) {
    #pragma unroll
    for (int r = 0; r < 4; ++r) {
      int row = r * 32 + srow_in_round;
      gl_lds16(&A[(size_t)(gm0 + row) * K + kt + skl], As + (r * 32 + (w << 3)) * 64);
      int brow = gn0 + row;
      if (GUARD_N) brow = brow < N ? brow : N - 1;
      gl_lds16(&B[(size_t)brow * K + kt + skl], Bs + (r * 32 + (w << 3)) * 64);
    }
    asm volatile("s_waitcnt vmcnt(0)" ::: "memory");
    __syncthreads();
    #pragma unroll
    for (int kk = 0; kk < 64; kk += 32) {
      short8 af[4], bfr[4];
      const int kb = (kk + (l >> 4) * 8) * 2;
      #pragma unroll
      for (int mt = 0; mt < 4; ++mt) {
        int row = wr * 64 + mt * 16 + (l & 15);
        af[mt] = *reinterpret_cast<const short8*>(reinterpret_cast<const char*>(As) + row * 128 + kb);
      }
      #pragma unroll
      for (int nt = 0; nt < 4; ++nt) {
        int row = wc * 64 + nt * 16 + (l & 15);
        bfr[nt] = *reinterpret_cast<const short8*>(reinterpret_cast<const char*>(Bs) + row * 128 + kb);
      }
      #pragma unroll
      for (int mt = 0; mt < 4; ++mt)
        #pragma unroll
        for (int nt = 0; nt < 4; ++nt)
          acc[mt][nt] = __builtin_amdgcn_mfma_f32_16x16x32_bf16(af[mt], bfr[nt], acc[mt][nt], 0, 0, 0);
    }
    __syncthreads();
  }
  #pragma unroll
  for (int mt = 0; mt < 4; ++mt)
    #pragma unroll
    for (int nt = 0; nt < 4; ++nt)
      #pragma unroll
      for (int i = 0; i < 4; ++i) {
        int row = wr * 64 + mt * 16 + (l >> 4) * 4 + i;
        int col = wc * 64 + nt * 16 + (l & 15);
        int gr = gm0 + row, gc = gn0 + col;
        if (!GUARD_N || gc < N) {
          float v = acc[mt][nt][i] + (BIAS_ON_M ? bias[gr] : bias[gc]);
          if (CB16) ((bf16*)Cv)[(size_t)gr * N + gc] = __float2bfloat16(v);
          else      ((float*)Cv)[(size_t)gr * N + gc] = v;
        }
      }
}

// ---------------------------------------------------------------------------
// Tree-GRU recurrence — BYTE-IDENTICAL to R7 (proven protocol).
// ---------------------------------------------------------------------------
__global__ __launch_bounds__(256) void k_recur(const bf16* __restrict__ whhp,
                                               const bf16* __restrict__ giT,
                                               const float* __restrict__ bghn,
                                               const int* __restrict__ edges,
                                               float* __restrict__ hf,
                                               bf16* __restrict__ hsteps,
                                               bf16* __restrict__ outs,
                                               unsigned* __restrict__ bar) {
  __shared__ float lds_p[4][64][52];
  const int tid = threadIdx.x, l = tid & 63, w = tid >> 6;
  const int ms = blockIdx.x >> 1, dh = blockIdx.x & 1;
  const int kw = w * 128;

  unsigned my_xcc = 0, my_desig = 0, my_xcdcnt = 0, my_nxcd = 0;
  if (tid == 0) {
    asm volatile("s_getreg_b32 %0, hwreg(HW_REG_XCC_ID)" : "=s"(my_xcc));
    my_xcc &= 7;
    unsigned prev = __hip_atomic_fetch_add(bar + REGC_OFF + dh * 8 + my_xcc, 1u,
                                           __ATOMIC_RELAXED, __HIP_MEMORY_SCOPE_AGENT);
    my_desig = (prev == 0);
    unsigned* sb = bar + SETUP_OFF + dh;
    __hip_atomic_fetch_add(sb, 1u, __ATOMIC_RELEASE, __HIP_MEMORY_SCOPE_AGENT);
    while (__hip_atomic_load(sb, __ATOMIC_RELAXED, __HIP_MEMORY_SCOPE_AGENT) < NWG_HALF)
      __builtin_amdgcn_s_sleep(2);
    __builtin_amdgcn_fence(__ATOMIC_ACQUIRE, "agent");
    my_xcdcnt = __hip_atomic_load(bar + REGC_OFF + dh * 8 + my_xcc,
                                  __ATOMIC_RELAXED, __HIP_MEMORY_SCOPE_AGENT);
    #pragma unroll
    for (int x = 0; x < 8; ++x)
      my_nxcd += (__hip_atomic_load(bar + REGC_OFF + dh * 8 + x,
                                    __ATOMIC_RELAXED, __HIP_MEMORY_SCOPE_AGENT) > 0u) ? 1u : 0u;
  }

  short8 areg[3][4];
  #pragma unroll
  for (int mt = 0; mt < 3; ++mt)
    #pragma unroll
    for (int ks = 0; ks < 4; ++ks) {
      int row = ms * 48 + mt * 16 + (l & 15);
      int k = kw + ks * 32 + (l >> 4) * 8;
      areg[mt][ks] = *reinterpret_cast<const short8*>(&whhp[(size_t)row * H_ + k]);
    }

  const int dl = tid >> 2;
  const int jp = (tid & 3) * 2;
  const int dg = dh * 64 + dl;
  const int jg0 = ms * 8 + jp;
  float bgh[12];
  #pragma unroll
  for (int q = 0; q < 12; ++q) bgh[q] = bghn[ms * 48 + jp * 6 + q];
  float hstate[2] = { hf[dg * H_ + jg0], hf[dg * H_ + jg0 + 1] };
  const bf16* gbase = giT + (size_t)(ms * 48 + jp * 6) * SD_ + dg;

  float gic[12]; int edc;
  #pragma unroll
  for (int q = 0; q < 12; ++q) gic[q] = __bfloat162float(gbase[(size_t)q * SD_]);
  edc = edges[dg];

  #pragma unroll 1
  for (int t = 0; t < S_; ++t) {
    float gin[12]; int edn;
    if (t + 1 < S_) {
      #pragma unroll
      for (int q = 0; q < 12; ++q) gin[q] = __bfloat162float(gbase[(size_t)q * SD_ + (t + 1) * D_]);
      edn = edges[(t + 1) * D_ + dg];
    } else {
      edn = 0;
      #pragma unroll
      for (int q = 0; q < 12; ++q) gin[q] = 0.f;
    }

    const bf16* hb = hsteps + (size_t)t * (D_ * H_);
    bf16* hnb = hsteps + (size_t)(t + 1) * (D_ * H_);

    short8 bfr[4][4];
    #pragma unroll
    for (int ks = 0; ks < 4; ++ks)
      #pragma unroll
      for (int nt = 0; nt < 4; ++nt) {
        int jb = w * 16 + ks * 4 + (l >> 4);
        int d = dh * 64 + nt * 16 + (l & 15);
        bfr[ks][nt] = *reinterpret_cast<const short8*>(hb + ((size_t)jb * D_ + d) * 8);
      }

    f32x4 acc[3][4];
    #pragma unroll
    for (int a = 0; a < 3; ++a)
      #pragma unroll
      for (int b = 0; b < 4; ++b) acc[a][b] = zero4();
    #pragma unroll
    for (int ks = 0; ks < 4; ++ks)
      #pragma unroll
      for (int mt = 0; mt < 3; ++mt)
        #pragma unroll
        for (int nt = 0; nt < 4; ++nt)
          acc[mt][nt] = __builtin_amdgcn_mfma_f32_16x16x32_bf16(areg[mt][ks], bfr[ks][nt], acc[mt][nt], 0, 0, 0);

    __syncthreads();
    #pragma unroll
    for (int mt = 0; mt < 3; ++mt)
      #pragma unroll
      for (int nt = 0; nt < 4; ++nt) {
        int col = nt * 16 + (l & 15);
        int r0 = mt * 16 + (l >> 4) * 4;
        *reinterpret_cast<f32x4*>(&lds_p[w][col][r0]) = acc[mt][nt];
      }
    __syncthreads();

    unsigned hpack;
    #pragma unroll
    for (int sl = 0; sl < 2; ++sl) {
      float gh[6];
      #pragma unroll
      for (int q = 0; q < 6; ++q) {
        int r = (jp + sl) * 6 + q;
        gh[q] = lds_p[0][dl][r] + lds_p[1][dl][r] + lds_p[2][dl][r]
              + lds_p[3][dl][r] + bgh[sl * 6 + q];
      }
      float rc = sigm(gic[sl * 6 + 0] + gh[0]);
      float zc = sigm(gic[sl * 6 + 1] + gh[1]);
      float nc = tanhf(gic[sl * 6 + 2] + rc * gh[2]);
      float rs = sigm(gic[sl * 6 + 3] + gh[3]);
      float zs = sigm(gic[sl * 6 + 4] + gh[4]);
      float ns = tanhf(gic[sl * 6 + 5] + rs * gh[5]);
      float ho = hstate[sl];
      float hc = (1.f - zc) * nc + zc * ho;
      float hs = (1.f - zs) * ns + zs * ho;
      float hv = (edc != 0) ? hc : hs;
      hstate[sl] = hv;
      bf16 hvb = __float2bfloat16(hv);
      reinterpret_cast<unsigned short*>(&hpack)[sl] = *reinterpret_cast<unsigned short*>(&hvb);
    }
    *reinterpret_cast<unsigned*>(hnb + ((size_t)ms * D_ + dg) * 8 + jp) = hpack;
    if (outs) {
      *reinterpret_cast<unsigned*>(&outs[(size_t)t * (D_ * H_) + dg * H_ + jg0]) = hpack;
    }
    edc = edn;
    #pragma unroll
    for (int q = 0; q < 12; ++q) gic[q] = gin[q];

    if (t + 1 < S_) {
      __syncthreads();
      if (tid == 0) {
        unsigned* xa = bar + XARR_OFF + ((dh * 8 + my_xcc) * SB_ + t);
        unsigned* gr = bar + GREADY_OFF + (dh * SB_ + t);
        unsigned* id = bar + INVD_OFF + ((dh * 8 + my_xcc) * SB_ + t);
        __hip_atomic_fetch_add(xa, 1u, __ATOMIC_RELAXED, __HIP_MEMORY_SCOPE_AGENT);
        if (my_desig) {
          while (__hip_atomic_load(xa, __ATOMIC_RELAXED, __HIP_MEMORY_SCOPE_AGENT) < my_xcdcnt)
            __builtin_amdgcn_s_sleep(1);
          __hip_atomic_fetch_add(gr, 1u, __ATOMIC_RELEASE, __HIP_MEMORY_SCOPE_AGENT);
          while (__hip_atomic_load(gr, __ATOMIC_RELAXED, __HIP_MEMORY_SCOPE_AGENT) < my_nxcd)
            __builtin_amdgcn_s_sleep(1);
          __builtin_amdgcn_fence(__ATOMIC_ACQUIRE, "agent");
          __hip_atomic_fetch_add(id, 1u, __ATOMIC_RELAXED, __HIP_MEMORY_SCOPE_AGENT);
        } else {
          while (__hip_atomic_load(id, __ATOMIC_RELAXED, __HIP_MEMORY_SCOPE_AGENT) < 1u)
            __builtin_amdgcn_s_sleep(1);
          __builtin_amdgcn_fence(__ATOMIC_ACQUIRE, "workgroup");
        }
      }
      __syncthreads();
    }
  }
  hf[dg * H_ + jg0]     = hstate[0];
  hf[dg * H_ + jg0 + 1] = hstate[1];
}

// ---------------------------------------------------------------------------
// Fused latent + decoder-init: per d-row, mean/logv/z (L=256) then
// dec_init h (H=512) from z kept in LDS. Single block row; reads complete
// (into LDS + syncthreads) before any write to the same row.
// ---------------------------------------------------------------------------
__global__ __launch_bounds__(256) void k_latdec(const float* __restrict__ hf,
    const float* __restrict__ h2mW, const float* __restrict__ h2mB,
    const float* __restrict__ h2lW, const float* __restrict__ h2lB,
    const float* __restrict__ eps,
    const float* __restrict__ l2hW, const float* __restrict__ l2hB,
    float* __restrict__ om, float* __restrict__ ov, float* __restrict__ oz,
    float* __restrict__ hfD, bf16* __restrict__ hx0) {
  __shared__ float hrow[H_];
  __shared__ float zrow[L_];
  const int d = blockIdx.x;
  for (int k = threadIdx.x; k < H_; k += 256) hrow[k] = hf[d * H_ + k];
  __syncthreads();
  const int lc = threadIdx.x;   // L_ == 256
  {
    const float* wm = &h2mW[(size_t)lc * H_];
    const float* wl = &h2lW[(size_t)lc * H_];
    float m = 0.f, v = 0.f;
    for (int k = 0; k < H_; ++k) { float h = hrow[k]; m += h * wm[k]; v += h * wl[k]; }
    m += h2mB[lc]; v += h2lB[lc];
    float z = eps[d * L_ + lc] * __expf(0.5f * v) + m;
    om[d * L_ + lc] = m; ov[d * L_ + lc] = v; oz[d * L_ + lc] = z;
    zrow[lc] = z;
  }
  __syncthreads();
  for (int j = threadIdx.x; j < H_; j += 256) {
    const float* wr = &l2hW[(size_t)j * L_];
    float a = 0.f;
    for (int k = 0; k < L_; ++k) a += zrow[k] * wr[k];
    a += l2hB[j];
    hfD[d * H_ + j] = a;
    hx0[((j >> 3) * D_ + d) * 8 + (j & 7)] = __float2bfloat16(a);
  }
}

// log-softmax over V=6000, in-place f32, float4-vectorized (R9-proven)
__global__ __launch_bounds__(256) void k_logsoftmax(float* __restrict__ lg) {
  __shared__ float buf[V_];
  __shared__ float redm[4], reds[4];
  constexpr int V4 = V_ / 4;   // 1500
  const size_t base4 = (size_t)blockIdx.x * V4;
  float4* g4 = reinterpret_cast<float4*>(lg) + base4;
  float4* b4 = reinterpret_cast<float4*>(buf);
  const int tid = threadIdx.x;
  float lmax = -3.0e38f;
  for (int i = tid; i < V4; i += 256) {
    float4 v = g4[i]; b4[i] = v;
    lmax = fmaxf(fmaxf(fmaxf(lmax, v.x), fmaxf(v.y, v.z)), v.w);
  }
  #pragma unroll
  for (int off = 32; off > 0; off >>= 1) lmax = fmaxf(lmax, __shfl_down(lmax, off, 64));
  if ((tid & 63) == 0) redm[tid >> 6] = lmax;
  __syncthreads();
  const float gmax = fmaxf(fmaxf(redm[0], redm[1]), fmaxf(redm[2], redm[3]));
  float s = 0.f;
  for (int i = tid; i < V4; i += 256) {
    float4 v = b4[i];
    s += __expf(v.x - gmax) + __expf(v.y - gmax) + __expf(v.z - gmax) + __expf(v.w - gmax);
  }
  #pragma unroll
  for (int off = 32; off > 0; off >>= 1) s += __shfl_down(s, off, 64);
  if ((tid & 63) == 0) reds[tid >> 6] = s;
  __syncthreads();
  const float lse = gmax + __logf(reds[0] + reds[1] + reds[2] + reds[3]);
  for (int i = tid; i < V4; i += 256) {
    float4 v = b4[i];
    v.x -= lse; v.y -= lse; v.z -= lse; v.w -= lse;
    g4[i] = v;
  }
}

// ---------------------------------------------------------------------------
extern "C" void kernel_launch(void* const* d_in, const int* in_sizes, int n_in,
                              void* d_out, int out_size, void* d_ws, size_t ws_size,
                              hipStream_t stream) {
  const int* nodes = (const int*)d_in[0];
  const int* edges = (const int*)d_in[1];
  const float* emb = (const float*)d_in[2];
  PrepArgs pa;
  for (int c = 0; c < 4; ++c) {
    pa.wih[c] = (const float*)d_in[3 + c * 4 + 0];
    pa.whh[c] = (const float*)d_in[3 + c * 4 + 1];
    pa.bih[c] = (const float*)d_in[3 + c * 4 + 2];
    pa.bhh[c] = (const float*)d_in[3 + c * 4 + 3];
  }
  const float* h2mW = (const float*)d_in[19];
  const float* h2mB = (const float*)d_in[20];
  const float* h2lW = (const float*)d_in[21];
  const float* h2lB = (const float*)d_in[22];
  const float* l2hW = (const float*)d_in[23];
  const float* l2hB = (const float*)d_in[24];
  const float* o2vW = (const float*)d_in[25];
  const float* o2vB = (const float*)d_in[26];
  const float* enc_init = (const float*)d_in[27];
  const float* eps = (const float*)d_in[28];

  char* ws = (char*)d_ws;
  size_t off = 0;
  bf16* WIHP = (bf16*)(ws + off); off += (size_t)2 * M3_ * H_ * 2;
  bf16* WHHP = (bf16*)(ws + off); off += (size_t)2 * M3_ * H_ * 2;
  float* BGI  = (float*)(ws + off); off += (size_t)2 * M3_ * 4;
  float* BGHN = (float*)(ws + off); off += (size_t)2 * M3_ * 4;
  bf16* XB   = (bf16*)(ws + off); off += (size_t)SD_ * H_ * 2;
  bf16* O2VB = (bf16*)(ws + off); off += (size_t)V_ * H_ * 2;
  float* HF  = (float*)(ws + off); off += (size_t)D_ * H_ * 4;
  bf16* HSTEPE = (bf16*)(ws + off); off += (size_t)(S_ + 1) * D_ * H_ * 2;  // 6.4 MB
  bf16* HSTEPD = (bf16*)(ws + off); off += (size_t)(S_ + 1) * D_ * H_ * 2;  // 6.4 MB
  bf16* OUTS = (bf16*)(ws + off); off += (size_t)S_ * D_ * H_ * 2;
  bf16* GITB = (bf16*)(ws + off); off += (size_t)M3_ * SD_ * 2;             // 37.7 MB
  unsigned* BAR = (unsigned*)(ws + off); off += 2 * BAR_WORDS * sizeof(unsigned);
  (void)ws_size; (void)in_sizes; (void)n_in; (void)out_size;

  float* out_logp = (float*)d_out;
  float* out_mean = out_logp + (size_t)SD_ * V_;
  float* out_logv = out_mean + (size_t)D_ * L_;
  float* out_z    = out_logv + (size_t)D_ * L_;

  // zero barrier counters every call (ws not re-poisoned between replays)
  hipMemsetAsync(BAR, 0, 2 * BAR_WORDS * sizeof(unsigned), stream);

  // prep
  hipLaunchKernelGGL(k_prep_w, dim3(2 * M3_), dim3(64), 0, stream, pa, WIHP, WHHP, BGI, BGHN);
  hipLaunchKernelGGL(k_gather_x, dim3(SD_ * H_ / 8 / 256), dim3(256), 0, stream, nodes, emb, XB);
  hipLaunchKernelGGL(k_cvt_bf16, dim3(V_ * H_ / 8 / 256), dim3(256), 0, stream, o2vW, O2VB, V_ * H_);
  hipLaunchKernelGGL(k_init_h, dim3((D_ * H_ + 255) / 256), dim3(256), 0, stream, enc_init, HF, HSTEPE);

  // encoder: gi GEMM (bf16 out) + recurrence
  hipLaunchKernelGGL((k_gemm<true, false, true>), dim3(SD_ / 128, M3_ / 128), dim3(256), 0, stream,
                     WIHP, XB, BGI, (void*)GITB, M3_, SD_);
  {
    const bf16* whhpE = WHHP; const bf16* gitp = GITB; const float* bghnE = BGHN;
    float* hfp = HF; bf16* hstep = HSTEPE; bf16* outs0 = nullptr;
    const int* edg = edges; unsigned* barE = BAR;
    void* args[] = {(void*)&whhpE, (void*)&gitp, (void*)&bghnE, (void*)&edg,
                    (void*)&hfp, (void*)&hstep, (void*)&outs0, (void*)&barE};
    hipLaunchCooperativeKernel((const void*)k_recur, dim3(128), dim3(256), args, 0, stream);
  }

  // fused latent + decoder-init (writes mean/logv/z outputs + HF + HSTEPD[0])
  hipLaunchKernelGGL(k_latdec, dim3(D_), dim3(256), 0, stream, HF, h2mW, h2mB, h2lW, h2lB,
                     eps, l2hW, l2hB, out_mean, out_logv, out_z, HF, HSTEPD);

  // decoder: gi GEMM + recurrence (writes OUTS)
  hipLaunchKernelGGL((k_gemm<true, false, true>), dim3(SD_ / 128, M3_ / 128), dim3(256), 0, stream,
                     WIHP + (size_t)M3_ * H_, XB, BGI + M3_, (void*)GITB, M3_, SD_);
  {
    const bf16* whhpD = WHHP + (size_t)M3_ * H_; const bf16* gitp = GITB;
    const float* bghnD = BGHN + M3_;
    float* hfp = HF; bf16* hstep = HSTEPD; bf16* outsP = OUTS;
    const int* edg = edges; unsigned* barD = BAR + BAR_WORDS;
    void* args[] = {(void*)&whhpD, (void*)&gitp, (void*)&bghnD, (void*)&edg,
                    (void*)&hfp, (void*)&hstep, (void*)&outsP, (void*)&barD};
    hipLaunchCooperativeKernel((const void*)k_recur, dim3(128), dim3(256), args, 0, stream);
  }

  // logits (f32 directly into d_out) + in-place log_softmax (R9-proven)
  hipLaunchKernelGGL((k_gemm<false, true, false>), dim3((V_ + 127) / 128, SD_ / 128), dim3(256), 0, stream,
                     OUTS, O2VB, o2vB, (void*)out_logp, SD_, V_);
  hipLaunchKernelGGL(k_logsoftmax, dim3(SD_), dim3(256), 0, stream, out_logp);
}